// Round 3
// baseline (217.619 us; speedup 1.0000x reference)
//
#include <hip/hip_runtime.h>

// Problem constants (from reference): B=8, C=3, H=512, W=512
constexpr int Cc = 3;
constexpr int HW = 512 * 512;            // 262144 = 2^18
constexpr int NPIX = 8 * HW;             // 2097152
constexpr int TPB  = 128;                // 2 waves per block
constexpr int TILE_PX = 512;             // pixels per tile
constexpr int NTILE = NPIX / TILE_PX;    // 4096 tiles
constexpr int TPBLK = 4;                 // tiles per block (pipelined)
constexpr int NBLK = NTILE / TPBLK;      // 1024 blocks

constexpr int T4  = TILE_PX * 3 / 4;     // 384 float4 of target per tile
constexpr int S4  = TILE_PX * 9 / 4;     // 1152 float4 of sigma per tile
constexpr int BUF4 = 2 * T4 + S4;        // 1920 float4 = 30 KB per buffer

// ws layout: [0, NBLK) doubles = per-block partial sums, then NBLK floats = maxes

__global__ __launch_bounds__(TPB, 1) void map_loss_main(
    const float* __restrict__ target,
    const float* __restrict__ mu,
    const float* __restrict__ sigma_y,
    double* __restrict__ part_sum,
    float* __restrict__ part_max)
{
    __shared__ float4 lds[2 * BUF4];     // 60 KB double buffer
    __shared__ double ssum[2];
    __shared__ float  smax[2];

    const int tid = threadIdx.x;
    const int bid = blockIdx.x;

    double local_sum = 0.0;
    float local_max = 0.0f;

    // ---- stage tile g into buffer bufsel: 15 global_load_lds per thread ----
    // dest is linear (wave-uniform base + lane*16, required); sigma source is
    // pre-swizzled by s ^ ((s>>6)&7) (wave-uniform XOR term -> still a
    // contiguous permuted block per instruction); read side applies same XOR.
    auto stage = [&](int g, int bufsel) {
        float4* bb = &lds[bufsel * BUF4];
        const long long px0 = (long long)g * TILE_PX;
        const int b  = (int)(px0 >> 18);
        const int hw = (int)px0 & (HW - 1);
        const long long cbase = (long long)b * (Cc * HW) + hw;   // float index
        const float4* tsrc = (const float4*)(target + cbase);
        const float4* msrc = (const float4*)(mu + cbase);
        #pragma unroll
        for (int k = 0; k < 3; ++k) {
            const int j = k * TPB + tid;                 // 0..383, linear
            __builtin_amdgcn_global_load_lds(
                (const __attribute__((address_space(1))) void*)(tsrc + k * (HW / 4) + tid),
                (__attribute__((address_space(3))) void*)(bb + j), 16, 0, 0);
            __builtin_amdgcn_global_load_lds(
                (const __attribute__((address_space(1))) void*)(msrc + k * (HW / 4) + tid),
                (__attribute__((address_space(3))) void*)(bb + T4 + j), 16, 0, 0);
        }
        const float4* ssrc = (const float4*)sigma_y + (long long)g * S4;
        #pragma unroll
        for (int k = 0; k < 9; ++k) {
            const int s = k * TPB + tid;                 // linear dest slot
            const int c = (s >> 6) & 7;                  // wave-uniform
            __builtin_amdgcn_global_load_lds(
                (const __attribute__((address_space(1))) void*)(ssrc + (s ^ c)),
                (__attribute__((address_space(3))) void*)(bb + 2 * T4 + s), 16, 0, 0);
        }
    };

    // ---- compute tile from buffer bufsel (pure LDS reads) ----
    auto compute = [&](int bufsel) {
        const float4* bb = &lds[bufsel * BUF4];
        float4 d0 = bb[0 * TPB + tid];
        float4 d1 = bb[1 * TPB + tid];
        float4 d2 = bb[2 * TPB + tid];
        const float4 m0 = bb[T4 + 0 * TPB + tid];
        const float4 m1 = bb[T4 + 1 * TPB + tid];
        const float4 m2 = bb[T4 + 2 * TPB + tid];
        d0.x -= m0.x; d0.y -= m0.y; d0.z -= m0.z; d0.w -= m0.w;
        d1.x -= m1.x; d1.y -= m1.y; d1.z -= m1.z; d1.w -= m1.w;
        d2.x -= m2.x; d2.y -= m2.y; d2.z -= m2.z; d2.w -= m2.w;

        union { float4 v[9]; float f[36]; } S;
        #pragma unroll
        for (int m = 0; m < 9; ++m) {
            const int r = 9 * tid + m;
            const int x = r ^ ((r >> 6) & 7);
            S.v[m] = bb[2 * T4 + x];
        }

        const float Tv0[4] = {d0.x, d0.y, d0.z, d0.w};
        const float Tv1[4] = {d1.x, d1.y, d1.z, d1.w};
        const float Tv2[4] = {d2.x, d2.y, d2.z, d2.w};

        #pragma unroll
        for (int i = 0; i < 4; ++i) {
            const float* s = S.f + i * 9;
            float s00 = s[0], s01 = s[1], s02 = s[2];
            float s11 = s[4], s12 = s[5], s22 = s[8];

            float a00 = s11 * s22 - s12 * s12;
            float a01 = s02 * s12 - s01 * s22;
            float a02 = s01 * s12 - s02 * s11;
            float a11 = s00 * s22 - s02 * s02;
            float a12 = s01 * s02 - s00 * s12;
            float a22 = s00 * s11 - s01 * s01;

            float det = s00 * a00 + s01 * a01 + s02 * a02;

            float t0 = Tv0[i], t1 = Tv1[i], t2 = Tv2[i];
            float quad = t0 * t0 * a00 + t1 * t1 * a11 + t2 * t2 * a22
                       + 2.0f * (t0 * t1 * a01 + t0 * t2 * a02 + t1 * t2 * a12);

            float t1term = 0.5f * quad / det;
            float t2term = 0.5f * logf(det);

            local_sum += (double)(t1term + t2term);
            local_max = fmaxf(local_max, t1term);
        }
    };

    const int g0 = bid * TPBLK;

    // ---- pipelined main loop: counted vmcnt, never drain mid-loop ----
    stage(g0 + 0, 0);
    stage(g0 + 1, 1);                                    // 30 loads/wave in flight

    // tile 0: wait oldest 15 (tile0), leave tile1's 15 in flight
    asm volatile("s_waitcnt vmcnt(15)" ::: "memory");
    __builtin_amdgcn_s_barrier();
    __builtin_amdgcn_sched_barrier(0);
    compute(0);
    __builtin_amdgcn_s_barrier();                        // all waves done reading buf0
    stage(g0 + 2, 0);

    // tile 1
    asm volatile("s_waitcnt vmcnt(15)" ::: "memory");
    __builtin_amdgcn_s_barrier();
    __builtin_amdgcn_sched_barrier(0);
    compute(1);
    __builtin_amdgcn_s_barrier();
    stage(g0 + 3, 1);

    // tile 2
    asm volatile("s_waitcnt vmcnt(15)" ::: "memory");
    __builtin_amdgcn_s_barrier();
    __builtin_amdgcn_sched_barrier(0);
    compute(0);
    __builtin_amdgcn_s_barrier();

    // tile 3 (last: drain)
    asm volatile("s_waitcnt vmcnt(0)" ::: "memory");
    __builtin_amdgcn_s_barrier();
    __builtin_amdgcn_sched_barrier(0);
    compute(1);

    // ---- reduction: 64-lane wave reduce, then 2-wave block reduce ----
    for (int off = 32; off > 0; off >>= 1) {
        local_sum += __shfl_down(local_sum, off, 64);
        local_max = fmaxf(local_max, __shfl_down(local_max, off, 64));
    }
    const int w = tid >> 6;
    const int lane = tid & 63;
    if (lane == 0) { ssum[w] = local_sum; smax[w] = local_max; }
    __syncthreads();

    if (tid == 0) {
        part_sum[bid] = ssum[0] + ssum[1];
        part_max[bid] = fmaxf(smax[0], smax[1]);
    }
}

__global__ __launch_bounds__(256) void map_loss_finalize(
    const double* __restrict__ part_sum,
    const float* __restrict__ part_max,
    float* __restrict__ out)
{
    double s = 0.0;
    float m = 0.0f;
    for (int i = threadIdx.x; i < NBLK; i += 256) {
        s += part_sum[i];
        m = fmaxf(m, part_max[i]);
    }

    for (int off = 32; off > 0; off >>= 1) {
        s += __shfl_down(s, off, 64);
        m = fmaxf(m, __shfl_down(m, off, 64));
    }

    __shared__ double ssum[4];
    __shared__ float  smax[4];
    int wave = threadIdx.x >> 6;
    int lane = threadIdx.x & 63;
    if (lane == 0) { ssum[wave] = s; smax[wave] = m; }
    __syncthreads();

    if (threadIdx.x == 0) {
        double bs = ssum[0] + ssum[1] + ssum[2] + ssum[3];
        float  bm = fmaxf(fmaxf(smax[0], smax[1]), fmaxf(smax[2], smax[3]));
        out[0] = (bm > 1e8f) ? 0.0f : (float)(bs / (double)NPIX);
    }
}

extern "C" void kernel_launch(void* const* d_in, const int* in_sizes, int n_in,
                              void* d_out, int out_size, void* d_ws, size_t ws_size,
                              hipStream_t stream) {
    const float* target  = (const float*)d_in[0];
    const float* mu      = (const float*)d_in[1];
    // d_in[2] = sigma_mu (unused), d_in[3] = sigma_n (unused)
    const float* sigma_y = (const float*)d_in[4];
    float* out = (float*)d_out;

    double* part_sum = (double*)d_ws;
    float*  part_max = (float*)((char*)d_ws + NBLK * sizeof(double));

    map_loss_main<<<NBLK, TPB, 0, stream>>>(target, mu, sigma_y, part_sum, part_max);
    map_loss_finalize<<<1, 256, 0, stream>>>(part_sum, part_max, out);
}